// Round 1
// baseline (1781.164 us; speedup 1.0000x reference)
//
#include <hip/hip_runtime.h>
#include <cmath>

// ---------------------------------------------------------------------------
// Model: 6x (conv3x3 + BN + ReLU), then LSTM(4096->256) over S=64, then
// tanh(linear) head. All fp32 (threshold 1.3e-4 forbids bf16 end-to-end).
// BN folded into conv weights by a tiny pre-pass kernel each launch.
// ---------------------------------------------------------------------------

__device__ __forceinline__ float sigmoidf_(float x) { return 1.f / (1.f + expf(-x)); }

// ---------------- fold BN into conv weights ----------------
// wf layout: [ic][OC][12] (9 taps padded to 12 for aligned b128 LDS reads)
__global__ __launch_bounds__(256) void fold_kernel(
    const float* __restrict__ w, const float* __restrict__ g,
    const float* __restrict__ b, const float* __restrict__ m,
    const float* __restrict__ v, float* __restrict__ wf,
    float* __restrict__ bias, int OC, int IC)
{
  int i = blockIdx.x * 256 + threadIdx.x;
  int total = OC * IC * 9;
  if (i < total) {
    int oc = i / (IC * 9);
    int r  = i % (IC * 9);
    int ic = r / 9;
    int k  = r % 9;
    float inv = g[oc] / sqrtf(v[oc] + 1e-5f);
    wf[(ic * OC + oc) * 12 + k] = w[i] * inv;
  }
  if (i < OC) {
    float inv = g[i] / sqrtf(v[i] + 1e-5f);
    bias[i] = b[i] - m[i] * inv;
  }
}

// ---------------- direct conv + bias + relu ----------------
// One block per image. Full padded input in LDS; weights staged in ic-chunks.
// Threads: WORKERS spatial workers (TPOS=4 consecutive x each) x GROUPS oc-groups.
// Weight reads are wave-uniform (broadcast) or 2-way -> conflict-free.
template<int IC, int OC, int IH, int IW, int STRIDE, int ICC, int TPOS>
__global__ __launch_bounds__(256, 2) void conv_bn_relu(
    const float* __restrict__ in, const float* __restrict__ wf,
    const float* __restrict__ bias, float* __restrict__ out)
{
  constexpr int OH = IH / STRIDE, OW = IW / STRIDE;
  constexpr int PIH = IH + 2, PIW = IW + 2;
  constexpr int NPOS = OH * OW;
  constexpr int WORKERS = NPOS / TPOS;
  constexpr int GROUPS = 256 / WORKERS;
  constexpr int TOC = OC / GROUPS;
  static_assert(GROUPS * TOC == OC, "bad tiling");
  constexpr int SPAN = (TPOS - 1) * STRIDE + 3;

  __shared__ float s_in[IC * PIH * PIW];
  __shared__ float s_w[ICC * OC * 12];
  __shared__ float s_bias[OC];

  const int n = blockIdx.x;
  const int tid = threadIdx.x;

  // zero (halo), load bias
  for (int i = tid; i < IC * PIH * PIW; i += 256) s_in[i] = 0.f;
  if (tid < OC) s_bias[tid] = bias[tid];
  __syncthreads();

  // stage interior with float4 (IW % 4 == 0 so no row crossing)
  const float* inN = in + (size_t)n * (IC * IH * IW);
  constexpr int NV = IC * IH * IW / 4;
  for (int i = tid; i < NV; i += 256) {
    float4 val = reinterpret_cast<const float4*>(inN)[i];
    int e = i * 4;
    int ic = e / (IH * IW);
    int rr = e % (IH * IW);
    int y = rr / IW, x = rr % IW;
    float* dst = &s_in[ic * PIH * PIW + (y + 1) * PIW + (x + 1)];
    dst[0] = val.x; dst[1] = val.y; dst[2] = val.z; dst[3] = val.w;
  }
  // (first weight-chunk __syncthreads covers staging)

  const int worker = tid % WORKERS;
  const int group  = tid / WORKERS;
  const int pos0 = worker * TPOS;
  const int oy  = pos0 / OW;
  const int ox0 = pos0 % OW;   // multiple of 4

  float acc[TOC][TPOS];
  #pragma unroll
  for (int a = 0; a < TOC; ++a)
    #pragma unroll
    for (int p = 0; p < TPOS; ++p) acc[a][p] = 0.f;

  for (int ic0 = 0; ic0 < IC; ic0 += ICC) {
    __syncthreads();
    constexpr int WV = ICC * OC * 12 / 4;
    const float4* wsrc = reinterpret_cast<const float4*>(wf + (size_t)ic0 * OC * 12);
    for (int i = tid; i < WV; i += 256)
      reinterpret_cast<float4*>(s_w)[i] = wsrc[i];
    __syncthreads();

    for (int icl = 0; icl < ICC; ++icl) {
      const float* sI = &s_in[(ic0 + icl) * (PIH * PIW)];
      float ir[3][SPAN];
      #pragma unroll
      for (int ky = 0; ky < 3; ++ky) {
        const float* rp = &sI[(oy * STRIDE + ky) * PIW + ox0 * STRIDE];
        #pragma unroll
        for (int x = 0; x < SPAN; ++x) ir[ky][x] = rp[x];
      }
      #pragma unroll
      for (int oc = 0; oc < TOC; ++oc) {
        const float* wp = &s_w[(icl * OC + group * TOC + oc) * 12];
        float wr[9];
        #pragma unroll
        for (int k = 0; k < 9; ++k) wr[k] = wp[k];
        #pragma unroll
        for (int p = 0; p < TPOS; ++p)
          #pragma unroll
          for (int ky = 0; ky < 3; ++ky)
            #pragma unroll
            for (int kx = 0; kx < 3; ++kx)
              acc[oc][p] = fmaf(ir[ky][p * STRIDE + kx], wr[ky * 3 + kx], acc[oc][p]);
      }
    }
  }

  float* outN = out + (size_t)n * (OC * OH * OW);
  #pragma unroll
  for (int oc = 0; oc < TOC; ++oc) {
    const int oco = group * TOC + oc;
    const float bb = s_bias[oco];
    float4 val;
    val.x = fmaxf(acc[oc][0] + bb, 0.f);
    val.y = fmaxf(acc[oc][1] + bb, 0.f);
    val.z = fmaxf(acc[oc][2] + bb, 0.f);
    val.w = fmaxf(acc[oc][3] + bb, 0.f);
    *reinterpret_cast<float4*>(outN + (size_t)oco * NPOS + oy * OW + ox0) = val;
  }
}

// ---------------- Xg = feats @ w_ih^T + (b_ih + b_hh) ----------------
// M=N=1024, K=4096. Row r = s*16+b maps to image n = b*64+s.
// 64x64 tile, BK=16, 4x4 per thread, double-buffered LDS.
__global__ __launch_bounds__(256) void gemm_xg(
    const float* __restrict__ feats, const float* __restrict__ w_ih,
    const float* __restrict__ b_ih, const float* __restrict__ b_hh,
    float* __restrict__ xg)
{
  __shared__ float s_a[2][16][68];
  __shared__ float s_b[2][16][68];
  const int tid = threadIdx.x;
  const int row0 = blockIdx.y * 64;
  const int col0 = blockIdx.x * 64;

  const int lrow = tid >> 2;   // 0..63
  const int kq   = tid & 3;    // 0..3

  const int r = row0 + lrow;
  const int n = (r & 15) * 64 + (r >> 4);
  const float* aptr = feats + (size_t)n * 4096 + kq * 4;
  const float* bptr = w_ih + (size_t)(col0 + lrow) * 4096 + kq * 4;

  const int tr = tid >> 4;     // 0..15
  const int tc = tid & 15;     // 0..15

  float acc[4][4] = {};

  float4 av = *(const float4*)(aptr);
  float4 bv = *(const float4*)(bptr);
  {
    int kb = kq * 4;
    s_a[0][kb+0][lrow] = av.x; s_a[0][kb+1][lrow] = av.y;
    s_a[0][kb+2][lrow] = av.z; s_a[0][kb+3][lrow] = av.w;
    s_b[0][kb+0][lrow] = bv.x; s_b[0][kb+1][lrow] = bv.y;
    s_b[0][kb+2][lrow] = bv.z; s_b[0][kb+3][lrow] = bv.w;
  }
  __syncthreads();

  for (int kc = 0; kc < 256; ++kc) {
    const int cur = kc & 1;
    if (kc < 255) {
      av = *(const float4*)(aptr + (size_t)(kc + 1) * 16);
      bv = *(const float4*)(bptr + (size_t)(kc + 1) * 16);
    }
    #pragma unroll
    for (int k = 0; k < 16; ++k) {
      float4 a4 = *(const float4*)&s_a[cur][k][tr * 4];
      float4 b4 = *(const float4*)&s_b[cur][k][tc * 4];
      float ar[4] = {a4.x, a4.y, a4.z, a4.w};
      float br[4] = {b4.x, b4.y, b4.z, b4.w};
      #pragma unroll
      for (int i = 0; i < 4; ++i)
        #pragma unroll
        for (int jj = 0; jj < 4; ++jj)
          acc[i][jj] = fmaf(ar[i], br[jj], acc[i][jj]);
    }
    if (kc < 255) {
      int kb = kq * 4, nb = cur ^ 1;
      s_a[nb][kb+0][lrow] = av.x; s_a[nb][kb+1][lrow] = av.y;
      s_a[nb][kb+2][lrow] = av.z; s_a[nb][kb+3][lrow] = av.w;
      s_b[nb][kb+0][lrow] = bv.x; s_b[nb][kb+1][lrow] = bv.y;
      s_b[nb][kb+2][lrow] = bv.z; s_b[nb][kb+3][lrow] = bv.w;
    }
    __syncthreads();
  }

  float4 bias4;
  {
    int jc = col0 + tc * 4;
    bias4.x = b_ih[jc+0] + b_hh[jc+0];
    bias4.y = b_ih[jc+1] + b_hh[jc+1];
    bias4.z = b_ih[jc+2] + b_hh[jc+2];
    bias4.w = b_ih[jc+3] + b_hh[jc+3];
  }
  #pragma unroll
  for (int i = 0; i < 4; ++i) {
    int rr = row0 + tr * 4 + i;
    float4 o;
    o.x = acc[i][0] + bias4.x;
    o.y = acc[i][1] + bias4.y;
    o.z = acc[i][2] + bias4.z;
    o.w = acc[i][3] + bias4.w;
    *(float4*)(xg + (size_t)rr * 1024 + col0 + tc * 4) = o;
  }
}

// ---------------- persistent LSTM recurrence ----------------
__device__ __forceinline__ void grid_barrier(int* cnt, int target) {
  __syncthreads();                       // drains each thread's vmcnt (stores in L2)
  if (threadIdx.x == 0) {
    __threadfence();                     // agent release: wb L2 to coherent point
    __hip_atomic_fetch_add(cnt, 1, __ATOMIC_ACQ_REL, __HIP_MEMORY_SCOPE_AGENT);
    while (__hip_atomic_load(cnt, __ATOMIC_RELAXED, __HIP_MEMORY_SCOPE_AGENT) < target)
      __builtin_amdgcn_s_sleep(2);
    __threadfence();                     // agent acquire: invalidate stale lines
  }
  __syncthreads();
}

// 256 blocks (one hidden unit j each; co-resident on 256 CUs), 256 threads.
// thread = (gate[2b], b[4b], c[2b]); each keeps a 64-float w_hh chunk in regs.
__global__ __launch_bounds__(256) void lstm_kernel(
    const float* __restrict__ xg, const float* __restrict__ w_hh,
    float* __restrict__ hs, int* counter)
{
  const int j = blockIdx.x;
  const int tid = threadIdx.x;
  const int gate = tid >> 6;
  const int b = (tid >> 2) & 15;
  const int c = tid & 3;

  float4 wv[16];
  {
    const float4* wrow = (const float4*)(w_hh + (size_t)(gate * 256 + j) * 256 + c * 64);
    #pragma unroll
    for (int q = 0; q < 16; ++q) wv[q] = wrow[q];
  }

  __shared__ float s_h[16 * 260];        // padded rows: breaks power-of-2 bank aliasing
  __shared__ float s_gates[4][16];
  __shared__ float s_c[16];
  if (tid < 16) s_c[tid] = 0.f;

  for (int s = 0; s < 64; ++s) {
    float gv = 0.f;
    if (s > 0) {
      const float4* hsrc = (const float4*)(hs + (size_t)(s - 1) * 4096);
      #pragma unroll
      for (int q = 0; q < 4; ++q) {
        int fi = tid + 256 * q;
        int bb = fi >> 6;
        int xq = fi & 63;
        ((float4*)(s_h + bb * 260))[xq] = hsrc[fi];
      }
      __syncthreads();
      const float4* hp = (const float4*)(s_h + b * 260 + c * 64);
      float p = 0.f;
      #pragma unroll
      for (int q = 0; q < 16; ++q) {
        float4 h4 = hp[q];
        p = fmaf(h4.x, wv[q].x, p);
        p = fmaf(h4.y, wv[q].y, p);
        p = fmaf(h4.z, wv[q].z, p);
        p = fmaf(h4.w, wv[q].w, p);
      }
      p += __shfl_xor(p, 1);
      p += __shfl_xor(p, 2);
      gv = p;
    }
    if (c == 0)
      s_gates[gate][b] = gv + xg[(size_t)(s * 16 + b) * 1024 + gate * 256 + j];
    __syncthreads();
    if (tid < 16) {
      float gi = s_gates[0][tid], gf = s_gates[1][tid];
      float gg = s_gates[2][tid], go = s_gates[3][tid];
      float cn = sigmoidf_(gf) * s_c[tid] + sigmoidf_(gi) * tanhf(gg);
      s_c[tid] = cn;
      hs[(size_t)s * 4096 + tid * 256 + j] = sigmoidf_(go) * tanhf(cn);
    }
    if (s < 63) grid_barrier(counter, 256 * (s + 1));
  }
}

// ---------------- classifier head ----------------
__global__ __launch_bounds__(64) void cls_kernel(
    const float* __restrict__ hs, const float* __restrict__ cw,
    const float* __restrict__ cb, float* __restrict__ out)
{
  const int id = blockIdx.x;             // b*53 + t
  const int b = id / 53;
  const int t = id % 53;
  const int s = 11 + t;
  const int lane = threadIdx.x;
  float4 hv = ((const float4*)(hs + (size_t)s * 4096 + b * 256))[lane];
  float4 wv = ((const float4*)cw)[lane];
  float p = hv.x * wv.x + hv.y * wv.y + hv.z * wv.z + hv.w * wv.w;
  #pragma unroll
  for (int off = 32; off >= 1; off >>= 1) p += __shfl_xor(p, off);
  if (lane == 0) out[id] = tanhf(p + cb[0]);
}

__global__ void init_kernel(int* counter) {
  if (threadIdx.x == 0) *counter = 0;
}

// ---------------------------------------------------------------------------
extern "C" void kernel_launch(void* const* d_in, const int* in_sizes, int n_in,
                              void* d_out, int out_size, void* d_ws, size_t ws_size,
                              hipStream_t stream)
{
  (void)in_sizes; (void)n_in; (void)out_size; (void)ws_size;
  const float* imgs = (const float*)d_in[0];
  const float *W[6], *G[6], *Bb[6], *M[6], *V[6];
  for (int i = 0; i < 6; ++i) {
    W[i]  = (const float*)d_in[1 + 5*i];
    G[i]  = (const float*)d_in[2 + 5*i];
    Bb[i] = (const float*)d_in[3 + 5*i];
    M[i]  = (const float*)d_in[4 + 5*i];
    V[i]  = (const float*)d_in[5 + 5*i];
  }
  const float* w_ih  = (const float*)d_in[31];
  const float* w_hh  = (const float*)d_in[32];
  const float* b_ih  = (const float*)d_in[33];
  const float* b_hh  = (const float*)d_in[34];
  const float* cls_w = (const float*)d_in[35];
  const float* cls_b = (const float*)d_in[36];
  float* out = (float*)d_out;

  // workspace layout (floats): actA(16.78M) actB(16.78M) xg(1.05M) hs(262K) wf bias counter
  float* ws   = (float*)d_ws;
  float* actA = ws;
  float* actB = actA + 16777216;
  float* xg   = actB + 16777216;
  float* hs   = xg + 1048576;
  float* wfp  = hs + 262144;
  static const int ocs[6] = {16, 16, 32, 32, 64, 64};
  static const int ics[6] = {3, 16, 16, 32, 32, 64};
  float* wf[6];
  size_t off = 0;
  for (int i = 0; i < 6; ++i) { wf[i] = wfp + off; off += (size_t)ocs[i] * ics[i] * 12; }
  float* biasp = wfp + off;
  float* bias[6];
  for (int i = 0; i < 6; ++i) bias[i] = biasp + i * 64;
  int* counter = (int*)(biasp + 6 * 64);

  init_kernel<<<1, 64, 0, stream>>>(counter);
  for (int i = 0; i < 6; ++i) {
    int total = ocs[i] * ics[i] * 9;
    fold_kernel<<<(total + 255) / 256, 256, 0, stream>>>(
        W[i], G[i], Bb[i], M[i], V[i], wf[i], bias[i], ocs[i], ics[i]);
  }
  conv_bn_relu<3, 16, 64, 64, 2, 3, 4><<<1024, 256, 0, stream>>>(imgs, wf[0], bias[0], actA);
  conv_bn_relu<16, 16, 32, 32, 1, 8, 4><<<1024, 256, 0, stream>>>(actA, wf[1], bias[1], actB);
  conv_bn_relu<16, 32, 32, 32, 2, 4, 4><<<1024, 256, 0, stream>>>(actB, wf[2], bias[2], actA);
  conv_bn_relu<32, 32, 16, 16, 1, 16, 4><<<1024, 256, 0, stream>>>(actA, wf[3], bias[3], actB);
  conv_bn_relu<32, 64, 16, 16, 2, 8, 4><<<1024, 256, 0, stream>>>(actB, wf[4], bias[4], actA);
  conv_bn_relu<64, 64, 8, 8, 1, 16, 4><<<1024, 256, 0, stream>>>(actA, wf[5], bias[5], actB);

  gemm_xg<<<dim3(16, 16, 1), 256, 0, stream>>>(actB, w_ih, b_ih, b_hh, xg);
  lstm_kernel<<<256, 256, 0, stream>>>(xg, w_hh, hs, counter);
  cls_kernel<<<848, 64, 0, stream>>>(hs, cls_w, cls_b, out);
}

// Round 2
// 880.625 us; speedup vs baseline: 2.0226x; 2.0226x over previous
//
#include <hip/hip_runtime.h>
#include <cmath>

// ---------------------------------------------------------------------------
// Model: 6x (conv3x3 + BN + ReLU), then LSTM(4096->256) over S=64, then
// tanh(linear) head. All fp32 (threshold 1.3e-4 forbids bf16 end-to-end).
// BN folded into conv weights by a tiny pre-pass kernel each launch.
//
// R2: LSTM rewritten. R1 used 256 blocks + ONE global atomic counter ->
// 17 us/step of serialized cross-XCD RMWs (VALUBusy 1%). Batch dim is
// parallel: now 16 independent groups of 4 blocks (one group per batch
// element), per-group counters on private cachelines, h exchanged via
// agent-scope atomic (write-through/coherent) loads & stores.
// ---------------------------------------------------------------------------

__device__ __forceinline__ float sigmoidf_(float x) { return 1.f / (1.f + expf(-x)); }

// ---------------- fold BN into conv weights ----------------
// wf layout: [ic][OC][12] (9 taps padded to 12 for aligned b128 LDS reads)
__global__ __launch_bounds__(256) void fold_kernel(
    const float* __restrict__ w, const float* __restrict__ g,
    const float* __restrict__ b, const float* __restrict__ m,
    const float* __restrict__ v, float* __restrict__ wf,
    float* __restrict__ bias, int OC, int IC)
{
  int i = blockIdx.x * 256 + threadIdx.x;
  int total = OC * IC * 9;
  if (i < total) {
    int oc = i / (IC * 9);
    int r  = i % (IC * 9);
    int ic = r / 9;
    int k  = r % 9;
    float inv = g[oc] / sqrtf(v[oc] + 1e-5f);
    wf[(ic * OC + oc) * 12 + k] = w[i] * inv;
  }
  if (i < OC) {
    float inv = g[i] / sqrtf(v[i] + 1e-5f);
    bias[i] = b[i] - m[i] * inv;
  }
}

// ---------------- direct conv + bias + relu ----------------
template<int IC, int OC, int IH, int IW, int STRIDE, int ICC, int TPOS>
__global__ __launch_bounds__(256, 2) void conv_bn_relu(
    const float* __restrict__ in, const float* __restrict__ wf,
    const float* __restrict__ bias, float* __restrict__ out)
{
  constexpr int OH = IH / STRIDE, OW = IW / STRIDE;
  constexpr int PIH = IH + 2, PIW = IW + 2;
  constexpr int NPOS = OH * OW;
  constexpr int WORKERS = NPOS / TPOS;
  constexpr int GROUPS = 256 / WORKERS;
  constexpr int TOC = OC / GROUPS;
  static_assert(GROUPS * TOC == OC, "bad tiling");
  constexpr int SPAN = (TPOS - 1) * STRIDE + 3;

  __shared__ float s_in[IC * PIH * PIW];
  __shared__ float s_w[ICC * OC * 12];
  __shared__ float s_bias[OC];

  const int n = blockIdx.x;
  const int tid = threadIdx.x;

  for (int i = tid; i < IC * PIH * PIW; i += 256) s_in[i] = 0.f;
  if (tid < OC) s_bias[tid] = bias[tid];
  __syncthreads();

  const float* inN = in + (size_t)n * (IC * IH * IW);
  constexpr int NV = IC * IH * IW / 4;
  for (int i = tid; i < NV; i += 256) {
    float4 val = reinterpret_cast<const float4*>(inN)[i];
    int e = i * 4;
    int ic = e / (IH * IW);
    int rr = e % (IH * IW);
    int y = rr / IW, x = rr % IW;
    float* dst = &s_in[ic * PIH * PIW + (y + 1) * PIW + (x + 1)];
    dst[0] = val.x; dst[1] = val.y; dst[2] = val.z; dst[3] = val.w;
  }

  const int worker = tid % WORKERS;
  const int group  = tid / WORKERS;
  const int pos0 = worker * TPOS;
  const int oy  = pos0 / OW;
  const int ox0 = pos0 % OW;

  float acc[TOC][TPOS];
  #pragma unroll
  for (int a = 0; a < TOC; ++a)
    #pragma unroll
    for (int p = 0; p < TPOS; ++p) acc[a][p] = 0.f;

  for (int ic0 = 0; ic0 < IC; ic0 += ICC) {
    __syncthreads();
    constexpr int WV = ICC * OC * 12 / 4;
    const float4* wsrc = reinterpret_cast<const float4*>(wf + (size_t)ic0 * OC * 12);
    for (int i = tid; i < WV; i += 256)
      reinterpret_cast<float4*>(s_w)[i] = wsrc[i];
    __syncthreads();

    for (int icl = 0; icl < ICC; ++icl) {
      const float* sI = &s_in[(ic0 + icl) * (PIH * PIW)];
      float ir[3][SPAN];
      #pragma unroll
      for (int ky = 0; ky < 3; ++ky) {
        const float* rp = &sI[(oy * STRIDE + ky) * PIW + ox0 * STRIDE];
        #pragma unroll
        for (int x = 0; x < SPAN; ++x) ir[ky][x] = rp[x];
      }
      #pragma unroll
      for (int oc = 0; oc < TOC; ++oc) {
        const float* wp = &s_w[(icl * OC + group * TOC + oc) * 12];
        float wr[9];
        #pragma unroll
        for (int k = 0; k < 9; ++k) wr[k] = wp[k];
        #pragma unroll
        for (int p = 0; p < TPOS; ++p)
          #pragma unroll
          for (int ky = 0; ky < 3; ++ky)
            #pragma unroll
            for (int kx = 0; kx < 3; ++kx)
              acc[oc][p] = fmaf(ir[ky][p * STRIDE + kx], wr[ky * 3 + kx], acc[oc][p]);
      }
    }
  }

  float* outN = out + (size_t)n * (OC * OH * OW);
  #pragma unroll
  for (int oc = 0; oc < TOC; ++oc) {
    const int oco = group * TOC + oc;
    const float bb = s_bias[oco];
    float4 val;
    val.x = fmaxf(acc[oc][0] + bb, 0.f);
    val.y = fmaxf(acc[oc][1] + bb, 0.f);
    val.z = fmaxf(acc[oc][2] + bb, 0.f);
    val.w = fmaxf(acc[oc][3] + bb, 0.f);
    *reinterpret_cast<float4*>(outN + (size_t)oco * NPOS + oy * OW + ox0) = val;
  }
}

// ---------------- Xg = feats @ w_ih^T + (b_ih + b_hh) ----------------
__global__ __launch_bounds__(256) void gemm_xg(
    const float* __restrict__ feats, const float* __restrict__ w_ih,
    const float* __restrict__ b_ih, const float* __restrict__ b_hh,
    float* __restrict__ xg)
{
  __shared__ float s_a[2][16][68];
  __shared__ float s_b[2][16][68];
  const int tid = threadIdx.x;
  const int row0 = blockIdx.y * 64;
  const int col0 = blockIdx.x * 64;

  const int lrow = tid >> 2;
  const int kq   = tid & 3;

  const int r = row0 + lrow;
  const int n = (r & 15) * 64 + (r >> 4);
  const float* aptr = feats + (size_t)n * 4096 + kq * 4;
  const float* bptr = w_ih + (size_t)(col0 + lrow) * 4096 + kq * 4;

  const int tr = tid >> 4;
  const int tc = tid & 15;

  float acc[4][4] = {};

  float4 av = *(const float4*)(aptr);
  float4 bv = *(const float4*)(bptr);
  {
    int kb = kq * 4;
    s_a[0][kb+0][lrow] = av.x; s_a[0][kb+1][lrow] = av.y;
    s_a[0][kb+2][lrow] = av.z; s_a[0][kb+3][lrow] = av.w;
    s_b[0][kb+0][lrow] = bv.x; s_b[0][kb+1][lrow] = bv.y;
    s_b[0][kb+2][lrow] = bv.z; s_b[0][kb+3][lrow] = bv.w;
  }
  __syncthreads();

  for (int kc = 0; kc < 256; ++kc) {
    const int cur = kc & 1;
    if (kc < 255) {
      av = *(const float4*)(aptr + (size_t)(kc + 1) * 16);
      bv = *(const float4*)(bptr + (size_t)(kc + 1) * 16);
    }
    #pragma unroll
    for (int k = 0; k < 16; ++k) {
      float4 a4 = *(const float4*)&s_a[cur][k][tr * 4];
      float4 b4 = *(const float4*)&s_b[cur][k][tc * 4];
      float ar[4] = {a4.x, a4.y, a4.z, a4.w};
      float br[4] = {b4.x, b4.y, b4.z, b4.w};
      #pragma unroll
      for (int i = 0; i < 4; ++i)
        #pragma unroll
        for (int jj = 0; jj < 4; ++jj)
          acc[i][jj] = fmaf(ar[i], br[jj], acc[i][jj]);
    }
    if (kc < 255) {
      int kb = kq * 4, nb = cur ^ 1;
      s_a[nb][kb+0][lrow] = av.x; s_a[nb][kb+1][lrow] = av.y;
      s_a[nb][kb+2][lrow] = av.z; s_a[nb][kb+3][lrow] = av.w;
      s_b[nb][kb+0][lrow] = bv.x; s_b[nb][kb+1][lrow] = bv.y;
      s_b[nb][kb+2][lrow] = bv.z; s_b[nb][kb+3][lrow] = bv.w;
    }
    __syncthreads();
  }

  float4 bias4;
  {
    int jc = col0 + tc * 4;
    bias4.x = b_ih[jc+0] + b_hh[jc+0];
    bias4.y = b_ih[jc+1] + b_hh[jc+1];
    bias4.z = b_ih[jc+2] + b_hh[jc+2];
    bias4.w = b_ih[jc+3] + b_hh[jc+3];
  }
  #pragma unroll
  for (int i = 0; i < 4; ++i) {
    int rr = row0 + tr * 4 + i;
    float4 o;
    o.x = acc[i][0] + bias4.x;
    o.y = acc[i][1] + bias4.y;
    o.z = acc[i][2] + bias4.z;
    o.w = acc[i][3] + bias4.w;
    *(float4*)(xg + (size_t)rr * 1024 + col0 + tc * 4) = o;
  }
}

// ---------------- persistent LSTM recurrence (R2) ----------------
// 64 blocks x 1024 threads. Block = (batch b = bid>>2, slice g = bid&3).
// Block handles hidden units j in [g*64, g*64+64) for batch b: 256 w_hh rows
// (4 gates x 64 units). Thread t: row r = t>>2, k-quarter q = t&3 -> 64
// weight floats pinned in VGPRs. Sync: per-batch 4-block counter on its own
// cacheline; h exchanged via agent-scope (coherent) atomic loads/stores --
// no L2 writeback/invalidate, no global 256-way contention.
__global__ __launch_bounds__(1024) void lstm_kernel(
    const float* __restrict__ xg, const float* __restrict__ w_hh,
    float* __restrict__ hs, int* counters)
{
  const int b = blockIdx.x >> 2;
  const int g = blockIdx.x & 3;
  const int tid = threadIdx.x;
  const int r = tid >> 2;          // 0..255 : local gate-row
  const int q = tid & 3;           // 0..3   : k-quarter
  const int gate = r >> 6;         // 0..3
  const int jl = r & 63;           // 0..63  : local hidden unit
  const int j = g * 64 + jl;       // global hidden unit

  // pin w_hh[gate*256 + j][q*64 .. q*64+64) in registers (64 VGPRs)
  float4 wv[16];
  {
    const float4* wrow = (const float4*)(w_hh + ((size_t)(gate * 256 + j)) * 256 + q * 64);
    #pragma unroll
    for (int k = 0; k < 16; ++k) wv[k] = wrow[k];
  }

  __shared__ float s_h[4 * 72];          // k-quarter rows, stride 72 (16B-aligned, banks offset by 8)
  __shared__ float s_gates[4][64];

  int* cnt = counters + b * 64;          // per-batch counter, own cacheline
  float c_reg = 0.f;                     // cell state, held by threads tid<64

  for (int s = 0; s < 64; ++s) {
    float gv = 0.f;
    if (s > 0) {
      // load h(s-1) for batch b: 256 coherent scalar loads
      if (tid < 256) {
        float hv = __hip_atomic_load(&hs[(size_t)(s - 1) * 4096 + b * 256 + tid],
                                     __ATOMIC_RELAXED, __HIP_MEMORY_SCOPE_AGENT);
        s_h[(tid >> 6) * 72 + (tid & 63)] = hv;
      }
      __syncthreads();
      const float4* hp = (const float4*)&s_h[q * 72];
      float p = 0.f;
      #pragma unroll
      for (int k = 0; k < 16; ++k) {
        float4 h4 = hp[k];
        p = fmaf(h4.x, wv[k].x, p);
        p = fmaf(h4.y, wv[k].y, p);
        p = fmaf(h4.z, wv[k].z, p);
        p = fmaf(h4.w, wv[k].w, p);
      }
      p += __shfl_xor(p, 1);
      p += __shfl_xor(p, 2);
      gv = p;
    }
    if (q == 0)
      s_gates[gate][jl] = gv + xg[(size_t)(s * 16 + b) * 1024 + gate * 256 + j];
    __syncthreads();
    if (tid < 64) {
      float gi = s_gates[0][tid], gf = s_gates[1][tid];
      float gg = s_gates[2][tid], go = s_gates[3][tid];
      float cn = sigmoidf_(gf) * c_reg + sigmoidf_(gi) * tanhf(gg);
      c_reg = cn;
      float hv = sigmoidf_(go) * tanhf(cn);
      __hip_atomic_store(&hs[(size_t)s * 4096 + b * 256 + g * 64 + tid], hv,
                         __ATOMIC_RELAXED, __HIP_MEMORY_SCOPE_AGENT);
    }
    if (s < 63) {
      __syncthreads();                   // drains all waves' stores (vmcnt 0 before s_barrier)
      if (tid == 0) {
        __hip_atomic_fetch_add(cnt, 1, __ATOMIC_RELEASE, __HIP_MEMORY_SCOPE_AGENT);
        const int target = 4 * (s + 1);
        while (__hip_atomic_load(cnt, __ATOMIC_RELAXED, __HIP_MEMORY_SCOPE_AGENT) < target)
          __builtin_amdgcn_s_sleep(1);
        (void)__hip_atomic_load(cnt, __ATOMIC_ACQUIRE, __HIP_MEMORY_SCOPE_AGENT);
      }
      __syncthreads();
    }
  }
}

// ---------------- classifier head ----------------
__global__ __launch_bounds__(64) void cls_kernel(
    const float* __restrict__ hs, const float* __restrict__ cw,
    const float* __restrict__ cb, float* __restrict__ out)
{
  const int id = blockIdx.x;             // b*53 + t
  const int b = id / 53;
  const int t = id % 53;
  const int s = 11 + t;
  const int lane = threadIdx.x;
  float4 hv = ((const float4*)(hs + (size_t)s * 4096 + b * 256))[lane];
  float4 wv = ((const float4*)cw)[lane];
  float p = hv.x * wv.x + hv.y * wv.y + hv.z * wv.z + hv.w * wv.w;
  #pragma unroll
  for (int off = 32; off >= 1; off >>= 1) p += __shfl_xor(p, off);
  if (lane == 0) out[id] = tanhf(p + cb[0]);
}

__global__ void init_kernel(int* counters) {
  counters[threadIdx.x] = 0;             // 1024 ints: 16 counters @ 64-int stride
}

// ---------------------------------------------------------------------------
extern "C" void kernel_launch(void* const* d_in, const int* in_sizes, int n_in,
                              void* d_out, int out_size, void* d_ws, size_t ws_size,
                              hipStream_t stream)
{
  (void)in_sizes; (void)n_in; (void)out_size; (void)ws_size;
  const float* imgs = (const float*)d_in[0];
  const float *W[6], *G[6], *Bb[6], *M[6], *V[6];
  for (int i = 0; i < 6; ++i) {
    W[i]  = (const float*)d_in[1 + 5*i];
    G[i]  = (const float*)d_in[2 + 5*i];
    Bb[i] = (const float*)d_in[3 + 5*i];
    M[i]  = (const float*)d_in[4 + 5*i];
    V[i]  = (const float*)d_in[5 + 5*i];
  }
  const float* w_ih  = (const float*)d_in[31];
  const float* w_hh  = (const float*)d_in[32];
  const float* b_ih  = (const float*)d_in[33];
  const float* b_hh  = (const float*)d_in[34];
  const float* cls_w = (const float*)d_in[35];
  const float* cls_b = (const float*)d_in[36];
  float* out = (float*)d_out;

  // workspace layout (floats): actA(16.78M) actB(16.78M) xg(1.05M) hs(262K) wf bias counters
  float* ws   = (float*)d_ws;
  float* actA = ws;
  float* actB = actA + 16777216;
  float* xg   = actB + 16777216;
  float* hs   = xg + 1048576;
  float* wfp  = hs + 262144;
  static const int ocs[6] = {16, 16, 32, 32, 64, 64};
  static const int ics[6] = {3, 16, 16, 32, 32, 64};
  float* wf[6];
  size_t off = 0;
  for (int i = 0; i < 6; ++i) { wf[i] = wfp + off; off += (size_t)ocs[i] * ics[i] * 12; }
  float* biasp = wfp + off;
  float* bias[6];
  for (int i = 0; i < 6; ++i) bias[i] = biasp + i * 64;
  int* counters = (int*)(biasp + 6 * 64);

  init_kernel<<<1, 1024, 0, stream>>>(counters);
  for (int i = 0; i < 6; ++i) {
    int total = ocs[i] * ics[i] * 9;
    fold_kernel<<<(total + 255) / 256, 256, 0, stream>>>(
        W[i], G[i], Bb[i], M[i], V[i], wf[i], bias[i], ocs[i], ics[i]);
  }
  conv_bn_relu<3, 16, 64, 64, 2, 3, 4><<<1024, 256, 0, stream>>>(imgs, wf[0], bias[0], actA);
  conv_bn_relu<16, 16, 32, 32, 1, 8, 4><<<1024, 256, 0, stream>>>(actA, wf[1], bias[1], actB);
  conv_bn_relu<16, 32, 32, 32, 2, 4, 4><<<1024, 256, 0, stream>>>(actB, wf[2], bias[2], actA);
  conv_bn_relu<32, 32, 16, 16, 1, 16, 4><<<1024, 256, 0, stream>>>(actA, wf[3], bias[3], actB);
  conv_bn_relu<32, 64, 16, 16, 2, 8, 4><<<1024, 256, 0, stream>>>(actB, wf[4], bias[4], actA);
  conv_bn_relu<64, 64, 8, 8, 1, 16, 4><<<1024, 256, 0, stream>>>(actA, wf[5], bias[5], actB);

  gemm_xg<<<dim3(16, 16, 1), 256, 0, stream>>>(actB, w_ih, b_ih, b_hh, xg);
  lstm_kernel<<<64, 1024, 0, stream>>>(xg, w_hh, hs, counters);
  cls_kernel<<<848, 64, 0, stream>>>(hs, cls_w, cls_b, out);
}

// Round 4
// 785.282 us; speedup vs baseline: 2.2682x; 1.1214x over previous
//
#include <hip/hip_runtime.h>
#include <cmath>

// ---------------------------------------------------------------------------
// 6x (conv3x3+BN+ReLU) -> LSTM(4096->256) over S=64 -> tanh(linear). fp32.
// R4 = R3 + halo fix: SPLITY staging now computes the valid input-row range
// at runtime (R3 hardcoded VR=RIH-1, dropping the last real row for the
// bottom half of the stride-2 split layer -> absmax 5.4e-4).
// ---------------------------------------------------------------------------

__device__ __forceinline__ float sigmoidf_(float x) { return 1.f / (1.f + expf(-x)); }

// ---------------- fold BN into conv weights ----------------
// wf layout: [ic][OC][12] (9 taps padded to 12 for aligned b128 LDS reads)
__global__ __launch_bounds__(256) void fold_kernel(
    const float* __restrict__ w, const float* __restrict__ g,
    const float* __restrict__ b, const float* __restrict__ m,
    const float* __restrict__ v, float* __restrict__ wf,
    float* __restrict__ bias, int OC, int IC)
{
  int i = blockIdx.x * 256 + threadIdx.x;
  int total = OC * IC * 9;
  if (i < total) {
    int oc = i / (IC * 9);
    int r  = i % (IC * 9);
    int ic = r / 9;
    int k  = r % 9;
    float inv = g[oc] / sqrtf(v[oc] + 1e-5f);
    wf[(ic * OC + oc) * 12 + k] = w[i] * inv;
  }
  if (i < OC) {
    float inv = g[i] / sqrtf(v[i] + 1e-5f);
    bias[i] = b[i] - m[i] * inv;
  }
}

// ---------------- direct conv + bias + relu ----------------
// PIW = IW+4 so row bases are 16B-aligned and every thread's tap window
// [xb .. xb+SPAN) sits inside NW aligned float4s (static lane selection).
// SPLITY: blocks per image (row split). NIMG: images per block (weight reuse).
template<int IC, int OC, int IH, int IW, int STRIDE, int ICC, int TPOS,
         int SPLITY, int NIMG>
__global__ __launch_bounds__(256, 2) void conv_bn_relu(
    const float* __restrict__ in, const float* __restrict__ wf,
    const float* __restrict__ bias, float* __restrict__ out)
{
  constexpr int OH = IH / STRIDE, OW = IW / STRIDE;
  constexpr int OHB = OH / SPLITY;                       // out rows per block
  constexpr int RIH = (SPLITY == 1) ? (IH + 2) : ((OHB - 1) * STRIDE + 3);
  constexpr int PIW = IW + 4;                            // mult of 4
  constexpr int PLANE = RIH * PIW;
  constexpr int NPOS = OHB * OW;
  constexpr int WORKERS = NPOS / TPOS;
  constexpr int GROUPS = 256 / WORKERS;
  constexpr int TOC = OC / GROUPS;
  static_assert(GROUPS * TOC == OC && WORKERS * GROUPS == 256, "bad tiling");
  constexpr int SPAN = (TPOS - 1) * STRIDE + 3;
  constexpr int NW = (SPAN + 3) / 4;                     // float4s per window row

  __shared__ float s_in[NIMG * IC * PLANE];
  __shared__ float s_w[ICC * OC * 12];
  __shared__ float s_bias[OC];

  const int tid = threadIdx.x;
  const int n0    = (SPLITY == 1) ? blockIdx.x * NIMG : blockIdx.x / SPLITY;
  const int split = (SPLITY == 1) ? 0 : blockIdx.x % SPLITY;
  const int ry0 = split * OHB;               // global out-row offset
  const int r0  = ry0 * STRIDE - 1;          // input row mapped to LDS row 0
  // valid input-row range [rv0, rv1] clipped to the image (runtime: differs
  // per split for stride-2; R3's compile-time VR=RIH-1 was the bug)
  const int rv0 = (r0 < 0) ? 0 : r0;
  const int rv1e = r0 + RIH - 1;
  const int rv1 = (rv1e > IH - 1) ? (IH - 1) : rv1e;
  const int VRr = rv1 - rv0 + 1;

  for (int i = tid; i < NIMG * IC * PLANE; i += 256) s_in[i] = 0.f;
  if (tid < OC) s_bias[tid] = bias[tid];
  __syncthreads();                           // memset before interior writes

  // stage interior: float4 global read -> 4 scalar LDS writes (col offset +1)
  constexpr int ROWF4 = IW / 4;
  const int NSTG = NIMG * IC * VRr * ROWF4;
  for (int i = tid; i < NSTG; i += 256) {
    int rw = i % ROWF4;
    int t  = i / ROWF4;
    int row = t % VRr;
    int ci  = t / VRr;                       // img*IC + ic
    int img = ci / IC, ic = ci % IC;
    int giy = rv0 + row;
    float4 val = *(const float4*)(in + (((size_t)(n0 + img) * IC + ic) * IH + giy) * IW + rw * 4);
    float* dst = &s_in[(ci * RIH + (giy - r0)) * PIW + 1 + rw * 4];
    dst[0] = val.x; dst[1] = val.y; dst[2] = val.z; dst[3] = val.w;
  }
  // first chunk's __syncthreads covers staging

  const int worker = tid % WORKERS;
  const int group  = tid / WORKERS;
  const int pos0 = worker * TPOS;
  const int oy  = pos0 / OW;
  const int ox0 = pos0 % OW;
  const int xb  = ox0 * STRIDE;              // aligned window start (mult of 4)

  float acc[NIMG][TOC][TPOS];
  #pragma unroll
  for (int im = 0; im < NIMG; ++im)
    #pragma unroll
    for (int a = 0; a < TOC; ++a)
      #pragma unroll
      for (int p = 0; p < TPOS; ++p) acc[im][a][p] = 0.f;

  for (int ic0 = 0; ic0 < IC; ic0 += ICC) {
    __syncthreads();
    constexpr int WV = ICC * OC * 12 / 4;
    const float4* wsrc = reinterpret_cast<const float4*>(wf + (size_t)ic0 * OC * 12);
    for (int i = tid; i < WV; i += 256)
      reinterpret_cast<float4*>(s_w)[i] = wsrc[i];
    __syncthreads();

    for (int icl = 0; icl < ICC; ++icl) {
      float win[NIMG][3][NW * 4];
      #pragma unroll
      for (int im = 0; im < NIMG; ++im)
        #pragma unroll
        for (int ky = 0; ky < 3; ++ky) {
          const float4* wp4 = (const float4*)
            &s_in[((im * IC + ic0 + icl) * RIH + oy * STRIDE + ky) * PIW + xb];
          #pragma unroll
          for (int w = 0; w < NW; ++w) {
            float4 t = wp4[w];
            win[im][ky][4*w+0] = t.x; win[im][ky][4*w+1] = t.y;
            win[im][ky][4*w+2] = t.z; win[im][ky][4*w+3] = t.w;
          }
        }
      #pragma unroll
      for (int oc = 0; oc < TOC; ++oc) {
        const float4* wp = (const float4*)&s_w[(icl * OC + group * TOC + oc) * 12];
        float4 w0 = wp[0], w1 = wp[1], w2 = wp[2];
        const float wr[9] = {w0.x, w0.y, w0.z, w0.w, w1.x, w1.y, w1.z, w1.w, w2.x};
        #pragma unroll
        for (int im = 0; im < NIMG; ++im)
          #pragma unroll
          for (int p = 0; p < TPOS; ++p)
            #pragma unroll
            for (int ky = 0; ky < 3; ++ky)
              #pragma unroll
              for (int kx = 0; kx < 3; ++kx)
                acc[im][oc][p] = fmaf(win[im][ky][p * STRIDE + kx],
                                      wr[ky * 3 + kx], acc[im][oc][p]);
      }
    }
  }

  #pragma unroll
  for (int im = 0; im < NIMG; ++im) {
    float* outN = out + (size_t)(n0 + im) * (OC * OH * OW);
    #pragma unroll
    for (int oc = 0; oc < TOC; ++oc) {
      const int oco = group * TOC + oc;
      const float bb = s_bias[oco];
      float* op = outN + ((size_t)oco * OH + (ry0 + oy)) * OW + ox0;
      #pragma unroll
      for (int vq = 0; vq < TPOS / 4; ++vq) {
        float4 val;
        val.x = fmaxf(acc[im][oc][vq*4+0] + bb, 0.f);
        val.y = fmaxf(acc[im][oc][vq*4+1] + bb, 0.f);
        val.z = fmaxf(acc[im][oc][vq*4+2] + bb, 0.f);
        val.w = fmaxf(acc[im][oc][vq*4+3] + bb, 0.f);
        *reinterpret_cast<float4*>(op + vq * 4) = val;
      }
    }
  }
}

// ---------------- Xg partials: split-K GEMM ----------------
// M=N=1024, K=4096 split in 2 halves (blockIdx.z). 64x64 tile, BK=16,
// 4x4/thread, double-buffered LDS. 512 blocks -> 2 blocks/CU.
__global__ __launch_bounds__(256) void gemm_xg(
    const float* __restrict__ feats, const float* __restrict__ w_ih,
    float* __restrict__ part)
{
  __shared__ float s_a[2][16][68];
  __shared__ float s_b[2][16][68];
  const int tid = threadIdx.x;
  const int row0 = blockIdx.y * 64;
  const int col0 = blockIdx.x * 64;
  const int kbase = blockIdx.z * 2048;
  float* outp = part + (size_t)blockIdx.z * 1048576;

  const int lrow = tid >> 2;
  const int kq   = tid & 3;

  const int r = row0 + lrow;
  const int n = (r & 15) * 64 + (r >> 4);     // xg row s*16+b <- image b*64+s
  const float* aptr = feats + (size_t)n * 4096 + kbase + kq * 4;
  const float* bptr = w_ih + (size_t)(col0 + lrow) * 4096 + kbase + kq * 4;

  const int tr = tid >> 4;
  const int tc = tid & 15;

  float acc[4][4] = {};

  float4 av = *(const float4*)(aptr);
  float4 bv = *(const float4*)(bptr);
  {
    int kb = kq * 4;
    s_a[0][kb+0][lrow] = av.x; s_a[0][kb+1][lrow] = av.y;
    s_a[0][kb+2][lrow] = av.z; s_a[0][kb+3][lrow] = av.w;
    s_b[0][kb+0][lrow] = bv.x; s_b[0][kb+1][lrow] = bv.y;
    s_b[0][kb+2][lrow] = bv.z; s_b[0][kb+3][lrow] = bv.w;
  }
  __syncthreads();

  for (int kc = 0; kc < 128; ++kc) {
    const int cur = kc & 1;
    if (kc < 127) {
      av = *(const float4*)(aptr + (size_t)(kc + 1) * 16);
      bv = *(const float4*)(bptr + (size_t)(kc + 1) * 16);
    }
    #pragma unroll
    for (int k = 0; k < 16; ++k) {
      float4 a4 = *(const float4*)&s_a[cur][k][tr * 4];
      float4 b4 = *(const float4*)&s_b[cur][k][tc * 4];
      float ar[4] = {a4.x, a4.y, a4.z, a4.w};
      float br[4] = {b4.x, b4.y, b4.z, b4.w};
      #pragma unroll
      for (int i = 0; i < 4; ++i)
        #pragma unroll
        for (int jj = 0; jj < 4; ++jj)
          acc[i][jj] = fmaf(ar[i], br[jj], acc[i][jj]);
    }
    if (kc < 127) {
      int kb = kq * 4, nb = cur ^ 1;
      s_a[nb][kb+0][lrow] = av.x; s_a[nb][kb+1][lrow] = av.y;
      s_a[nb][kb+2][lrow] = av.z; s_a[nb][kb+3][lrow] = av.w;
      s_b[nb][kb+0][lrow] = bv.x; s_b[nb][kb+1][lrow] = bv.y;
      s_b[nb][kb+2][lrow] = bv.z; s_b[nb][kb+3][lrow] = bv.w;
    }
    __syncthreads();
  }

  #pragma unroll
  for (int i = 0; i < 4; ++i) {
    int rr = row0 + tr * 4 + i;
    float4 o;
    o.x = acc[i][0]; o.y = acc[i][1]; o.z = acc[i][2]; o.w = acc[i][3];
    *(float4*)(outp + (size_t)rr * 1024 + col0 + tc * 4) = o;
  }
}

// xg = p0 + p1 + (b_ih + b_hh)
__global__ __launch_bounds__(256) void reduce_xg(
    const float* __restrict__ p, const float* __restrict__ b_ih,
    const float* __restrict__ b_hh, float* __restrict__ xg)
{
  int i = blockIdx.x * 256 + threadIdx.x;          // float4 index, 262144 total
  float4 a = ((const float4*)p)[i];
  float4 c = ((const float4*)p)[i + 262144];
  int cb = i & 255;                                 // column float4 index
  float4 bi = ((const float4*)b_ih)[cb];
  float4 bh = ((const float4*)b_hh)[cb];
  float4 o;
  o.x = a.x + c.x + bi.x + bh.x;
  o.y = a.y + c.y + bi.y + bh.y;
  o.z = a.z + c.z + bi.z + bh.z;
  o.w = a.w + c.w + bi.w + bh.w;
  ((float4*)xg)[i] = o;
}

// ---------------- persistent LSTM recurrence ----------------
// 64 blocks x 1024 threads; block = (batch b, slice g). h values published as
// (tag=step+1, value) 64-bit pairs via relaxed agent-scope atomics; consumers
// spin directly on the pairs they need -- no counters, no fences, one one-way
// coherence hop per step. ws poison 0xAAAAAAAA never matches tags 1..64.
__global__ __launch_bounds__(1024) void lstm_kernel(
    const float* __restrict__ xg, const float* __restrict__ w_hh,
    float* __restrict__ hs, unsigned long long* __restrict__ hpair)
{
  const int b = blockIdx.x >> 2;
  const int g = blockIdx.x & 3;
  const int tid = threadIdx.x;
  const int r = tid >> 2;          // 0..255 gate-row
  const int q = tid & 3;           // k-quarter
  const int gate = r >> 6;
  const int jl = r & 63;
  const int j = g * 64 + jl;

  float4 wv[16];
  {
    const float4* wrow = (const float4*)(w_hh + ((size_t)(gate * 256 + j)) * 256 + q * 64);
    #pragma unroll
    for (int k = 0; k < 16; ++k) wv[k] = wrow[k];
  }

  __shared__ float s_h[4 * 72];
  __shared__ float s_gates[4][64];
  float c_reg = 0.f;

  for (int s = 0; s < 64; ++s) {
    float xv = 0.f;
    if (q == 0) xv = xg[(size_t)(s * 16 + b) * 1024 + gate * 256 + j];  // in flight during spin
    float gv = 0.f;
    if (s > 0) {
      if (tid < 256) {
        const unsigned long long* src = hpair + ((size_t)(s - 1) * 16 + b) * 256 + tid;
        unsigned long long pv;
        do {
          pv = __hip_atomic_load(src, __ATOMIC_RELAXED, __HIP_MEMORY_SCOPE_AGENT);
        } while ((unsigned int)(pv >> 32) != (unsigned int)s);
        s_h[(tid >> 6) * 72 + (tid & 63)] = __uint_as_float((unsigned int)pv);
      }
      __syncthreads();
      const float4* hp = (const float4*)&s_h[q * 72];
      float p = 0.f;
      #pragma unroll
      for (int k = 0; k < 16; ++k) {
        float4 h4 = hp[k];
        p = fmaf(h4.x, wv[k].x, p);
        p = fmaf(h4.y, wv[k].y, p);
        p = fmaf(h4.z, wv[k].z, p);
        p = fmaf(h4.w, wv[k].w, p);
      }
      p += __shfl_xor(p, 1);
      p += __shfl_xor(p, 2);
      gv = p;
    }
    if (q == 0) s_gates[gate][jl] = gv + xv;
    __syncthreads();
    if (tid < 64) {
      float gi = s_gates[0][tid], gf = s_gates[1][tid];
      float gg = s_gates[2][tid], go = s_gates[3][tid];
      float cn = sigmoidf_(gf) * c_reg + sigmoidf_(gi) * tanhf(gg);
      c_reg = cn;
      float hv = sigmoidf_(go) * tanhf(cn);
      hs[(size_t)s * 4096 + b * 256 + g * 64 + tid] = hv;      // plain, for cls
      unsigned long long pv =
          ((unsigned long long)(unsigned int)(s + 1) << 32) | __float_as_uint(hv);
      __hip_atomic_store(hpair + ((size_t)s * 16 + b) * 256 + g * 64 + tid, pv,
                         __ATOMIC_RELAXED, __HIP_MEMORY_SCOPE_AGENT);
    }
    // no end-of-step barrier: next-iter s_h/s_gates writes are ordered behind
    // this iter's barriers; peer data exchange is tag-driven.
  }
}

// ---------------- classifier head ----------------
__global__ __launch_bounds__(64) void cls_kernel(
    const float* __restrict__ hs, const float* __restrict__ cw,
    const float* __restrict__ cb, float* __restrict__ out)
{
  const int id = blockIdx.x;             // b*53 + t
  const int b = id / 53;
  const int t = id % 53;
  const int s = 11 + t;
  const int lane = threadIdx.x;
  float4 hv = ((const float4*)(hs + (size_t)s * 4096 + b * 256))[lane];
  float4 wv = ((const float4*)cw)[lane];
  float p = hv.x * wv.x + hv.y * wv.y + hv.z * wv.z + hv.w * wv.w;
  #pragma unroll
  for (int off = 32; off >= 1; off >>= 1) p += __shfl_xor(p, off);
  if (lane == 0) out[id] = tanhf(p + cb[0]);
}

// ---------------------------------------------------------------------------
extern "C" void kernel_launch(void* const* d_in, const int* in_sizes, int n_in,
                              void* d_out, int out_size, void* d_ws, size_t ws_size,
                              hipStream_t stream)
{
  (void)in_sizes; (void)n_in; (void)out_size; (void)ws_size;
  const float* imgs = (const float*)d_in[0];
  const float *W[6], *G[6], *Bb[6], *M[6], *V[6];
  for (int i = 0; i < 6; ++i) {
    W[i]  = (const float*)d_in[1 + 5*i];
    G[i]  = (const float*)d_in[2 + 5*i];
    Bb[i] = (const float*)d_in[3 + 5*i];
    M[i]  = (const float*)d_in[4 + 5*i];
    V[i]  = (const float*)d_in[5 + 5*i];
  }
  const float* w_ih  = (const float*)d_in[31];
  const float* w_hh  = (const float*)d_in[32];
  const float* b_ih  = (const float*)d_in[33];
  const float* b_hh  = (const float*)d_in[34];
  const float* cls_w = (const float*)d_in[35];
  const float* cls_b = (const float*)d_in[36];
  float* out = (float*)d_out;

  // ws layout (floats): actA(16.78M, reused as gemm partials) actB(16.78M)
  // xg(1.05M) hs(262K) hpair(524K as u64) wf bias
  float* ws   = (float*)d_ws;
  float* actA = ws;
  float* actB = actA + 16777216;
  float* xg   = actB + 16777216;
  float* hs   = xg + 1048576;
  unsigned long long* hpair = (unsigned long long*)(hs + 262144);
  float* wfp  = hs + 262144 + 524288;
  static const int ocs[6] = {16, 16, 32, 32, 64, 64};
  static const int ics[6] = {3, 16, 16, 32, 32, 64};
  float* wf[6];
  size_t off = 0;
  for (int i = 0; i < 6; ++i) { wf[i] = wfp + off; off += (size_t)ocs[i] * ics[i] * 12; }
  float* biasp = wfp + off;
  float* bias[6];
  for (int i = 0; i < 6; ++i) bias[i] = biasp + i * 64;

  for (int i = 0; i < 6; ++i) {
    int total = ocs[i] * ics[i] * 9;
    fold_kernel<<<(total + 255) / 256, 256, 0, stream>>>(
        W[i], G[i], Bb[i], M[i], V[i], wf[i], bias[i], ocs[i], ics[i]);
  }

  //                IC  OC  IH  IW  S  ICC TP SPL NI
  conv_bn_relu< 3, 16, 64, 64, 2,  3, 8, 1, 1><<<1024, 256, 0, stream>>>(imgs,  wf[0], bias[0], actA);
  conv_bn_relu<16, 16, 32, 32, 1,  8, 8, 2, 1><<<2048, 256, 0, stream>>>(actA, wf[1], bias[1], actB);
  conv_bn_relu<16, 32, 32, 32, 2,  8, 4, 2, 1><<<2048, 256, 0, stream>>>(actB, wf[2], bias[2], actA);
  conv_bn_relu<32, 32, 16, 16, 1,  8, 8, 1, 1><<<1024, 256, 0, stream>>>(actA, wf[3], bias[3], actB);
  conv_bn_relu<32, 64, 16, 16, 2,  8, 4, 1, 1><<<1024, 256, 0, stream>>>(actB, wf[4], bias[4], actA);
  conv_bn_relu<64, 64,  8,  8, 1,  4, 8, 1, 2><<< 512, 256, 0, stream>>>(actA, wf[5], bias[5], actB);

  gemm_xg<<<dim3(16, 16, 2), 256, 0, stream>>>(actB, w_ih, actA);   // partials in actA
  reduce_xg<<<1024, 256, 0, stream>>>(actA, b_ih, b_hh, xg);
  lstm_kernel<<<64, 1024, 0, stream>>>(xg, w_hh, hs, hpair);
  cls_kernel<<<848, 64, 0, stream>>>(hs, cls_w, cls_b, out);
}